// Round 8
// baseline (319.099 us; speedup 1.0000x reference)
//
#include <hip/hip_runtime.h>
#include <math.h>

// CrossViewSwapAttention forward. Round 8: persistent-W multi-chunk GEMM with
// register A-prefetch (k_gemmP), fp32 residual trunk (CUR/Q1/Q2) for absmax
// margin. 13 dispatches.
// B=2 N=6 H=W=64 FH=32 FW=88 DIM=128 HEADS=4 DH=32 QW=8x8 KW=4x11

typedef __attribute__((ext_vector_type(8))) short short8;
typedef __attribute__((ext_vector_type(4))) float f32x4;

__device__ __forceinline__ unsigned short f2bf(float f){
  union { float f; unsigned u; } v; v.f = f;
  unsigned r = v.u + 0x7FFF + ((v.u >> 16) & 1);   // RNE
  return (unsigned short)(r >> 16);
}
__device__ __forceinline__ float bf2f(unsigned short h){
  union { unsigned u; float f; } v; v.u = ((unsigned)h) << 16; return v.f;
}
__device__ __forceinline__ void store_bf16x8(unsigned short* p, const float* v){
  union { short8 s8; unsigned short u[8]; } u;
  #pragma unroll
  for (int i=0;i<8;i++) u.u[i] = f2bf(v[i]);
  *(short8*)p = u.s8;
}

// gelu(x) = 0.5 x (1 + erf(x/sqrt2)); erf via A&S 7.1.26, |err| <= 1.5e-7.
__device__ __forceinline__ float gelu_erf(float x){
  float z = x * 0.70710678118654752f;
  float a = fabsf(z);
  float t = 1.0f / fmaf(0.3275911f, a, 1.0f);
  float p = t*(0.254829592f + t*(-0.284496736f + t*(1.421413741f +
            t*(-1.453152027f + t*1.061405429f))));
  float er = 1.0f - p*__expf(-a*a);
  er = copysignf(er, z);
  return 0.5f * x * (1.0f + er);
}

__device__ __forceinline__ size_t remap_kv(int tok, int mode){
  // tok = bn*2816 + i*88 + j  ->  KP/VP row ((b*64+l)*264 + t)
  int bn = tok / 2816; int p = tok - bn*2816;
  int b = bn / 6, n = bn - b*6;
  int i = p / 88, j = p - i*88;
  int l, t;
  if (mode == 1){            // stage 1: _win(k, 4, 11)
    int jw = j / 11;
    l = (i >> 2)*8 + jw;
    t = n*44 + (i & 3)*11 + (j - jw*11);
  } else {                   // stage 2: _gridwin(k, 4, 11)
    l = (i & 7)*8 + (j & 7);
    t = n*44 + (i >> 3)*11 + (j >> 3);
  }
  return (size_t)((b*64 + l)*264 + t);
}

// ---------------- fused prep: wprep | geom | bevq2 (cembed inline) ----------
__global__ __launch_bounds__(128) void k_prep(
    const float* __restrict__ qkv, const float* __restrict__ wp,
    const float* __restrict__ wma, const float* __restrict__ wmb,
    const float* __restrict__ wfl, const float* __restrict__ wfp,
    unsigned short* __restrict__ Wt,
    const float* __restrict__ Iinv, const float* __restrict__ Einv,
    const float* __restrict__ Wimg, const float* __restrict__ Wcam,
    unsigned short* __restrict__ K1h,
    const float* __restrict__ gridp, const float* __restrict__ Wbev,
    const float* __restrict__ bbev, const float* __restrict__ x,
    const float* __restrict__ lg, const float* __restrict__ lb,
    unsigned short* __restrict__ Qh){
  __shared__ float sx[128][9];
  int bid = blockIdx.x;
  if (bid < 64){
    const int sel[16]  = {0,0,0,0,0,0, 1,1, 2,2, 3,3,3,3, 4,5};
    const int soff[16] = {0,16384,32768,49152,65536,81920, 0,16384, 0,32768,
                          0,16384,32768,49152, 0,0};
    const int doff[16] = {0,16384,32768,49152,65536,81920, 98304,114688,
                          131072,163840, 196608,212992,229376,245760, 262144,278528};
    const int Ns[16]   = {128,128,128,128,128,128, 128,128, 256,256,
                          128,128,128,128, 128,128};
    const int trs[16]  = {1,1,1,1,1,1, 1,1, 1,1, 1,1,1,1, 0,0};
    int sg = bid >> 2, q = bid & 3;
    const float* srcs[6] = {qkv, wp, wma, wmb, wfl, wfp};
    const float* src = srcs[sel[sg]] + soff[sg];
    unsigned short* dst = Wt + doff[sg];
    int K = 128, N = Ns[sg];
    int quarter = (K*N) >> 2;
    for (int idx = q*quarter + threadIdx.x; idx < (q+1)*quarter; idx += 128){
      int n = idx / K, k = idx - n*K;
      float v = trs[sg] ? src[k*N + n] : src[idx];
      dst[idx] = f2bf(v);
    }
  } else if (bid < 4288){
    int tile = bid - 64;
    int bn = tile / 352; int p0 = (tile - bn*352)*8;
    int xid = threadIdx.x >> 4, part = threadIdx.x & 15;
    int p = p0 + xid;
    int i = p / 88, j = p - i*88;
    float xs = (float)j * (480.0f/87.0f);
    float ys = (float)i * (224.0f/31.0f);
    const float* I = Iinv + bn*9;
    const float* E = Einv + bn*16;
    float c0 = I[0]*xs + I[1]*ys + I[2];
    float c1 = I[3]*xs + I[4]*ys + I[5];
    float c2 = I[6]*xs + I[7]*ys + I[8];
    float d0 = E[0]*c0 + E[1]*c1 + E[2]*c2 + E[3];
    float d1 = E[4]*c0 + E[5]*c1 + E[6]*c2 + E[7];
    float d2 = E[8]*c0 + E[9]*c1 + E[10]*c2 + E[11];
    float d3 = E[12]*c0 + E[13]*c1 + E[14]*c2 + E[15];
    float v[8]; float sq = 0.f;
    #pragma unroll
    for (int k=0;k<8;k++){
      int o = part*8 + k;
      const float* W = Wimg + o*4;
      const float* Wc = Wcam + o*4;
      float de = W[0]*d0 + W[1]*d1 + W[2]*d2 + W[3]*d3;
      float ce = Wc[0]*E[3] + Wc[1]*E[7] + Wc[2]*E[11] + Wc[3]*E[15];
      float vv = de - ce;
      v[k] = vv; sq = fmaf(vv, vv, sq);
    }
    #pragma unroll
    for (int off=8; off>0; off>>=1) sq += __shfl_xor(sq, off, 16);
    float rn = 1.0f / fmaxf(sqrtf(sq), 1e-12f);
    float o8[8];
    #pragma unroll
    for (int k=0;k<8;k++) o8[k] = v[k]*rn;
    store_bf16x8(K1h + (size_t)(bn*2816 + p)*128 + part*8, o8);
  } else {
    int tile = bid - 4288;
    int bn = tile >> 9; int pp0 = (tile & 511) << 3;
    int b = bn / 6, n = bn - b*6;
    {
      const float* xr = x + (size_t)b*524288 + (size_t)threadIdx.x*4096 + pp0;
      float4 a0 = *(const float4*)xr;
      float4 a1 = *(const float4*)(xr + 4);
      sx[threadIdx.x][0]=a0.x; sx[threadIdx.x][1]=a0.y;
      sx[threadIdx.x][2]=a0.z; sx[threadIdx.x][3]=a0.w;
      sx[threadIdx.x][4]=a1.x; sx[threadIdx.x][5]=a1.y;
      sx[threadIdx.x][6]=a1.z; sx[threadIdx.x][7]=a1.w;
    }
    __syncthreads();
    int xid = threadIdx.x >> 4, part = threadIdx.x & 15;
    int pix = pp0 + xid;
    int h = pix >> 6, w = pix & 63;
    const float* E = Einv + bn*16;
    float g0 = gridp[pix], g1 = gridp[4096 + pix];
    float v[8]; float sq = 0.f;
    #pragma unroll
    for (int k=0;k<8;k++){
      int o = part*8 + k;
      const float* Wc = Wcam + o*4;
      float ce = Wc[0]*E[3] + Wc[1]*E[7] + Wc[2]*E[11] + Wc[3]*E[15];
      float we = Wbev[o*2]*g0 + Wbev[o*2+1]*g1 + bbev[o];
      float vv = we - ce;
      v[k] = vv; sq = fmaf(vv, vv, sq);
    }
    #pragma unroll
    for (int off=8; off>0; off>>=1) sq += __shfl_xor(sq, off, 16);
    float rn = 1.0f / fmaxf(sqrtf(sq), 1e-12f);
    float q[8]; float s=0.f, s2=0.f;
    #pragma unroll
    for (int k=0;k<8;k++){
      q[k] = fmaf(v[k], rn, sx[part*8+k][xid]);
      s += q[k]; s2 = fmaf(q[k], q[k], s2);
    }
    #pragma unroll
    for (int off=8; off>0; off>>=1){ s += __shfl_xor(s, off, 16); s2 += __shfl_xor(s2, off, 16); }
    float mean = s*(1.f/128.f);
    float rstd = rsqrtf(fmaxf(s2*(1.f/128.f) - mean*mean, 0.f) + 1e-5f);
    int l = (h>>3)*8 + (w>>3);
    int t = n*64 + (h&7)*8 + (w&7);
    size_t row = (size_t)((b*64 + l)*384 + t);
    float o8[8];
    #pragma unroll
    for (int k=0;k<8;k++){
      int c = part*8 + k;
      o8[k] = fmaf((q[k]-mean)*rstd, lg[c], lb[c]);
    }
    store_bf16x8(Qh + row*128 + part*8, o8);
  }
}

// ---------------- persistent-W multi-chunk GEMM with A prefetch -------------
struct GArg {
  const unsigned short* Xh; const float* Xf; int ldx;
  const float* lg; const float* lb;          // LN params, or BN params if conv
  const unsigned short* Wt; const float* bias;
  unsigned short* OUTH; float* OUTF; int ldout; float oscale;
  int do_ln; int act; int outmode; int skip_mode; int conv;
  const float* skipf; const unsigned short* skiph; int ldskip;
  int nchunks; int nblocks;
};

template<int MT>
__global__ __launch_bounds__(256) void k_gemmP(GArg ga, GArg gb, GArg gc,
                                               int s1, int s2){
  constexpr int KP_ = 136;
  constexpr int MTILES = MT / 16;
  constexpr int TPR = 256 / MT;
  constexpr int KPT = 128 / TPR;
  __shared__ unsigned short sW[128*KP_];
  __shared__ unsigned short sA[MT*KP_];
  __shared__ unsigned short sD[MT*KP_];
  __shared__ float sg[128], sb[128], sbias[128];
  const int b0 = (int)blockIdx.x;
  const GArg g = (b0 < s1) ? ga : (b0 < s2) ? gb : gc;
  const int bid0 = (b0 < s1) ? b0 : (b0 < s2) ? b0 - s1 : b0 - s2;
  const int tid = threadIdx.x;
  for (int i = tid; i < 2048; i += 256){
    int n = i >> 4, k8 = (i & 15) << 3;
    *(short8*)&sW[n*KP_ + k8] = *(const short8*)(g.Wt + (size_t)n*128 + k8);
  }
  if (tid < 128){
    if (g.do_ln || g.conv){ sg[tid]=g.lg[tid]; sb[tid]=g.lb[tid]; }
    sbias[tid] = g.bias ? g.bias[tid] : 0.f;
  }
  int r, part;
  if (g.conv){ r = tid & 63; part = tid >> 6; }       // MT=64 only
  else { r = tid / TPR; part = tid % TPR; }
  const float RSQ = rsqrtf(1.0f + 1e-5f);
  const int lane = tid & 63, wv = tid >> 6;
  const int lane15 = lane & 15, quad = lane >> 4;
  const int n0 = wv * 32;
  float va[KPT], vb[KPT];

  auto loadA = [&](int ch, float* v){
    int base = ch * MT;
    if (g.conv){
      int bn = base / 2816;
      int p = base - bn*2816 + r;
      const float* fb = g.Xf + ((size_t)bn*128 + part*KPT)*2816 + p;
      #pragma unroll
      for (int i=0;i<KPT;i++) v[i] = fb[(size_t)i*2816];
    } else if (g.Xf){
      const float* src = g.Xf + (size_t)(base + r)*g.ldx + part*KPT;
      #pragma unroll
      for (int k=0;k<KPT;k+=4){
        float4 t = *(const float4*)(src + k);
        v[k]=t.x; v[k+1]=t.y; v[k+2]=t.z; v[k+3]=t.w;
      }
    } else {
      const unsigned short* src = g.Xh + (size_t)(base + r)*g.ldx + part*KPT;
      #pragma unroll
      for (int k=0;k<KPT;k+=8){
        union { short8 s; unsigned short u[8]; } t;
        t.s = *(const short8*)(src + k);
        #pragma unroll
        for (int i2=0;i2<8;i2++) v[k+i2] = bf2f(t.u[i2]);
      }
    }
  };

  if (bid0 < g.nchunks) loadA(bid0, va);
  for (int ch = bid0; ch < g.nchunks; ch += g.nblocks){
    const int base = ch * MT;
    // phase1: transform va, write sA
    if (g.conv){
      #pragma unroll
      for (int i=0;i<KPT;i++){
        int c = part*KPT + i;
        va[i] = fmaxf(fmaf(va[i]*RSQ, sg[c], sb[c]), 0.f);
      }
    } else if (g.do_ln){
      float s=0.f, s2=0.f;
      #pragma unroll
      for (int k=0;k<KPT;k++){ s += va[k]; s2 = fmaf(va[k],va[k],s2); }
      #pragma unroll
      for (int off=TPR/2; off>0; off>>=1){
        s += __shfl_xor(s, off, TPR); s2 += __shfl_xor(s2, off, TPR);
      }
      float mean = s * (1.f/128.f);
      float rstd = rsqrtf(fmaxf(s2*(1.f/128.f) - mean*mean, 0.f) + 1e-5f);
      #pragma unroll
      for (int k=0;k<KPT;k++){
        int c = part*KPT + k;
        va[k] = fmaf((va[k]-mean)*rstd, sg[c], sb[c]);
      }
    }
    {
      unsigned short* dst = sA + r*KP_ + part*KPT;
      #pragma unroll
      for (int k=0;k<KPT;k+=8) store_bf16x8(dst+k, va+k);
    }
    __syncthreads();
    // phase2: prefetch next A, MFMA, epilogue
    {
      int nxt = ch + g.nblocks;
      loadA(nxt < g.nchunks ? nxt : ch, vb);
    }
    f32x4 acc[MTILES][2];
    #pragma unroll
    for (int mt=0; mt<MTILES; mt++){ acc[mt][0]=(f32x4)0.f; acc[mt][1]=(f32x4)0.f; }
    const unsigned short* aptr = sA + lane15*KP_ + quad*8;
    const unsigned short* bptr = sW + (size_t)(n0 + lane15)*KP_ + quad*8;
    #pragma unroll
    for (int kk=0; kk<4; kk++){
      short8 af[MTILES], bf2v[2];
      #pragma unroll
      for (int mt=0; mt<MTILES; mt++) af[mt] = *(const short8*)(aptr + mt*16*KP_ + kk*32);
      bf2v[0] = *(const short8*)(bptr + kk*32);
      bf2v[1] = *(const short8*)(bptr + 16*KP_ + kk*32);
      #pragma unroll
      for (int mt=0; mt<MTILES; mt++){
        acc[mt][0] = __builtin_amdgcn_mfma_f32_16x16x32_bf16(af[mt], bf2v[0], acc[mt][0], 0,0,0);
        acc[mt][1] = __builtin_amdgcn_mfma_f32_16x16x32_bf16(af[mt], bf2v[1], acc[mt][1], 0,0,0);
      }
    }
    #pragma unroll
    for (int mt=0; mt<MTILES; mt++){
      #pragma unroll
      for (int nt=0; nt<2; nt++){
        int col = n0 + nt*16 + lane15;
        float bsv = sbias[col];
        #pragma unroll
        for (int r4=0; r4<4; r4++){
          int row = mt*16 + quad*4 + r4;
          int rrow = base + row;
          float v = acc[mt][nt][r4] + bsv;
          if (g.act) v = gelu_erf(v);
          if (g.skip_mode == 1){
            int bb = rrow >> 12, l = (rrow >> 6) & 63, pp = rrow & 63;
            int pix = (((l>>3)*8 + (pp>>3)) << 6) + (l&7)*8 + (pp&7);
            v += g.skipf[(size_t)bb*524288 + (size_t)col*4096 + pix];
          } else if (g.skip_mode == 2){
            v += bf2f(g.skiph[(size_t)rrow*g.ldskip + col]);
          } else if (g.skip_mode == 3){
            v += g.skipf[(size_t)rrow*g.ldskip + col];
          }
          v *= g.oscale;
          if (g.OUTF) g.OUTF[(size_t)rrow*g.ldout + col] = v;
          else        sD[row*KP_ + col] = f2bf(v);
        }
      }
    }
    __syncthreads();
    if (g.OUTH){
      for (int i = tid; i < MT*16; i += 256){
        int row = i >> 4, seg = i & 15;
        int rrow = base + row;
        size_t orow = g.outmode ? remap_kv(rrow, g.outmode) : (size_t)rrow;
        *(short8*)(g.OUTH + orow*(size_t)g.ldout + seg*8) = *(const short8*)&sD[row*KP_ + seg*8];
      }
    }
    #pragma unroll
    for (int k=0;k<KPT;k++) va[k] = vb[k];
  }
}

// ---------------- KT=256 gemm (MLP down), fp32 skip + fp32 out --------------
__global__ __launch_bounds__(256) void k_gemm256(
    const unsigned short* __restrict__ Xh,           // rows ld 256 (H)
    const unsigned short* __restrict__ Wt1, const unsigned short* __restrict__ Wt2,
    const float* __restrict__ bias, float* __restrict__ OUTF,
    const float* __restrict__ skipf){
  constexpr int KP_ = 136;
  __shared__ unsigned short sW[128*KP_];
  __shared__ unsigned short sA[2*32*KP_];
  __shared__ float sbias[128];
  const int tid = threadIdx.x;
  const int base = blockIdx.x * 32;
  {
    const int r = tid >> 3, part = tid & 7;
    const unsigned short* src = Xh + (size_t)(base+r)*256 + part*32;
    unsigned short* dst = sA + (part>>2)*32*KP_ + r*KP_ + (part&3)*32;
    #pragma unroll
    for (int k=0;k<32;k+=8) *(short8*)(dst+k) = *(const short8*)(src+k);
  }
  for (int i = tid; i < 2048; i += 256){
    int n = i >> 4, k8 = (i & 15) << 3;
    *(short8*)&sW[n*KP_ + k8] = *(const short8*)(Wt1 + (size_t)n*128 + k8);
  }
  if (tid < 128) sbias[tid] = bias ? bias[tid] : 0.f;
  __syncthreads();
  const int lane = tid & 63, wv = tid >> 6;
  const int lane15 = lane & 15, quad = lane >> 4;
  const int n0 = wv * 32;
  f32x4 acc[2][2];
  acc[0][0]=(f32x4)0.f; acc[0][1]=(f32x4)0.f;
  acc[1][0]=(f32x4)0.f; acc[1][1]=(f32x4)0.f;
  #pragma unroll
  for (int half=0; half<2; half++){
    const unsigned short* aptr = sA + half*32*KP_ + lane15*KP_ + quad*8;
    const unsigned short* bptr = sW + (size_t)(n0 + lane15)*KP_ + quad*8;
    #pragma unroll
    for (int kk=0; kk<4; kk++){
      short8 a0 = *(const short8*)(aptr + kk*32);
      short8 a1 = *(const short8*)(aptr + 16*KP_ + kk*32);
      short8 b0 = *(const short8*)(bptr + kk*32);
      short8 b1 = *(const short8*)(bptr + 16*KP_ + kk*32);
      acc[0][0] = __builtin_amdgcn_mfma_f32_16x16x32_bf16(a0,b0,acc[0][0],0,0,0);
      acc[1][0] = __builtin_amdgcn_mfma_f32_16x16x32_bf16(a1,b0,acc[1][0],0,0,0);
      acc[0][1] = __builtin_amdgcn_mfma_f32_16x16x32_bf16(a0,b1,acc[0][1],0,0,0);
      acc[1][1] = __builtin_amdgcn_mfma_f32_16x16x32_bf16(a1,b1,acc[1][1],0,0,0);
    }
    if (half == 0){
      __syncthreads();
      for (int i = tid; i < 2048; i += 256){
        int n = i >> 4, k8 = (i & 15) << 3;
        *(short8*)&sW[n*KP_ + k8] = *(const short8*)(Wt2 + (size_t)n*128 + k8);
      }
      __syncthreads();
    }
  }
  #pragma unroll
  for (int mt=0; mt<2; mt++){
    #pragma unroll
    for (int nt=0; nt<2; nt++){
      int col = n0 + nt*16 + lane15;
      float bsv = sbias[col];
      #pragma unroll
      for (int r4=0; r4<4; r4++){
        int row = mt*16 + quad*4 + r4;
        float v = acc[mt][nt][r4] + bsv + skipf[(size_t)(base+row)*128 + col];
        OUTF[(size_t)(base+row)*128 + col] = v;
      }
    }
  }
}

// ---------------- MFMA attention: one block per (b,l,head), 4 waves ---------
__global__ __launch_bounds__(256) void k_attn2(const unsigned short* __restrict__ QPh,
    const unsigned short* __restrict__ KPh, const unsigned short* __restrict__ VPh,
    unsigned short* __restrict__ AOh, int nrep, int nQ){
  __shared__ unsigned short Ksh[288*40];
  __shared__ unsigned short Vt[32*296];
  __shared__ unsigned short Psh[4*16*40];
  __shared__ float rs[4*16];
  int hd = blockIdx.x & 3; int bl = blockIdx.x >> 2;
  size_t kvbase = (size_t)bl*264;
  int tid = threadIdx.x;
  for (int idx = tid; idx < 1056; idx += 256){
    int row = idx >> 2, seg = idx & 3;
    *(short8*)&Ksh[row*40 + seg*8] =
      *(const short8*)(KPh + (kvbase+row)*128 + hd*32 + seg*8);
  }
  for (int idx = tid; idx < 96; idx += 256){
    int row = 264 + (idx>>2), seg = idx & 3;
    short8 z = {0,0,0,0,0,0,0,0};
    *(short8*)&Ksh[row*40 + seg*8] = z;
  }
  for (int idx = tid; idx < 1056; idx += 256){
    int row = idx >> 2, seg = idx & 3;
    union { short8 s; unsigned short u[8]; } t;
    t.s = *(const short8*)(VPh + (kvbase+row)*128 + hd*32 + seg*8);
    #pragma unroll
    for (int i=0;i<8;i++) Vt[(seg*8+i)*296 + row] = t.u[i];
  }
  for (int idx = tid; idx < 384; idx += 256){
    int d = idx / 12, kp = 264 + (idx % 12)*2;
    *(unsigned*)&Vt[d*296 + kp] = 0u;
  }
  __syncthreads();
  const int wv = tid >> 6, lane = tid & 63;
  const int lane15 = lane & 15, quad = lane >> 4;
  unsigned short* Pw = Psh + wv*640;
  float* rsw = rs + wv*16;
  short8 vfrag[9][2];
  #pragma unroll
  for (int kc=0; kc<9; kc++){
    vfrag[kc][0] = *(const short8*)&Vt[(lane15)*296      + kc*32 + quad*8];
    vfrag[kc][1] = *(const short8*)&Vt[(16+lane15)*296   + kc*32 + quad*8];
  }
  f32x4 macc0 = (f32x4)0.f, macc1 = (f32x4)0.f;
  for (int cam = 0; cam < nrep; cam++){
    int qrow = bl*nQ + (cam*4 + wv)*16 + lane15;
    short8 qf = *(const short8*)(QPh + (size_t)qrow*128 + hd*32 + quad*8);
    f32x4 oa0 = (f32x4)0.f, oa1 = (f32x4)0.f;
    float rsum = 0.f;
    #pragma unroll
    for (int kc=0; kc<9; kc++){
      #pragma unroll
      for (int sub=0; sub<2; sub++){
        int kt = kc*2 + sub;
        short8 kf = *(const short8*)&Ksh[(kt*16 + lane15)*40 + quad*8];
        f32x4 st = __builtin_amdgcn_mfma_f32_16x16x32_bf16(kf, qf, (f32x4)0.f, 0,0,0);
        int kbase = kt*16 + quad*4;
        float e0 = (kbase+0 < 264) ? __expf(st[0]) : 0.f;
        float e1 = (kbase+1 < 264) ? __expf(st[1]) : 0.f;
        float e2 = (kbase+2 < 264) ? __expf(st[2]) : 0.f;
        float e3 = (kbase+3 < 264) ? __expf(st[3]) : 0.f;
        rsum += (e0+e1)+(e2+e3);
        uint2 pk;
        pk.x = (unsigned)f2bf(e0) | ((unsigned)f2bf(e1) << 16);
        pk.y = (unsigned)f2bf(e2) | ((unsigned)f2bf(e3) << 16);
        *(uint2*)&Pw[lane15*40 + sub*16 + quad*4] = pk;
      }
      short8 pf = *(const short8*)&Pw[lane15*40 + quad*8];
      oa0 = __builtin_amdgcn_mfma_f32_16x16x32_bf16(pf, vfrag[kc][0], oa0, 0,0,0);
      oa1 = __builtin_amdgcn_mfma_f32_16x16x32_bf16(pf, vfrag[kc][1], oa1, 0,0,0);
    }
    rsum += __shfl_xor(rsum, 16);
    rsum += __shfl_xor(rsum, 32);
    if (lane < 16) rsw[lane] = rsum;
    f32x4 rv = *(f32x4*)&rsw[quad*4];
    #pragma unroll
    for (int r=0;r<4;r++){
      float inv = 1.f / rv[r];
      macc0[r] = fmaf(oa0[r], inv, macc0[r]);
      macc1[r] = fmaf(oa1[r], inv, macc1[r]);
    }
  }
  float sc = (nrep == 6) ? (1.f/6.f) : 1.f;
  int pixb = wv*16 + quad*4;
  #pragma unroll
  for (int r=0;r<4;r++){
    size_t rowo = ((size_t)(bl*64 + pixb + r))*128 + hd*32;
    AOh[rowo + lane15]      = f2bf(macc0[r]*sc);
    AOh[rowo + 16 + lane15] = f2bf(macc1[r]*sc);
  }
}

// ---------------- final LN (fp32 in) + transpose to (B,128,64,64) fp32 ------
__global__ __launch_bounds__(128) void k_final(const float* __restrict__ Xf,
    const float* __restrict__ g, const float* __restrict__ be,
    float* __restrict__ out){
  __shared__ float st[1024];
  __shared__ float sm[8], sr[8];
  int r0 = blockIdx.x*8;
  int b = r0 >> 12, l = (r0 >> 6) & 63, p0 = r0 & 63;
  int h = (l >> 3)*8 + (p0 >> 3);
  int wbase = (l & 7)*8;
  {
    const float* src = Xf + (size_t)r0*128 + threadIdx.x*8;
    float4 a0 = *(const float4*)src;
    float4 a1 = *(const float4*)(src + 4);
    st[threadIdx.x*8+0]=a0.x; st[threadIdx.x*8+1]=a0.y;
    st[threadIdx.x*8+2]=a0.z; st[threadIdx.x*8+3]=a0.w;
    st[threadIdx.x*8+4]=a1.x; st[threadIdx.x*8+5]=a1.y;
    st[threadIdx.x*8+6]=a1.z; st[threadIdx.x*8+7]=a1.w;
  }
  __syncthreads();
  int xid = threadIdx.x >> 4, part = threadIdx.x & 15;
  float s=0.f, s2=0.f;
  #pragma unroll
  for (int k=0;k<8;k++){
    float v = st[xid*128 + part*8 + k];
    s += v; s2 = fmaf(v,v,s2);
  }
  #pragma unroll
  for (int off=8; off>0; off>>=1){ s += __shfl_xor(s, off, 16); s2 += __shfl_xor(s2, off, 16); }
  if (part == 0){
    float mean = s*(1.f/128.f);
    sm[xid] = mean;
    sr[xid] = rsqrtf(fmaxf(s2*(1.f/128.f) - mean*mean, 0.f) + 1e-5f);
  }
  __syncthreads();
  int o = threadIdx.x;
  float go = g[o], bo = be[o];
  size_t obase = ((size_t)(b*128 + o))*4096 + h*64 + wbase;
  float res[8];
  #pragma unroll
  for (int xx=0; xx<8; xx++) res[xx] = fmaf((st[xx*128+o]-sm[xx])*sr[xx], go, bo);
  *(float4*)&out[obase]   = make_float4(res[0],res[1],res[2],res[3]);
  *(float4*)&out[obase+4] = make_float4(res[4],res[5],res[6],res[7]);
}

extern "C" void kernel_launch(void* const* d_in, const int* in_sizes, int n_in,
                              void* d_out, int out_size, void* d_ws, size_t ws_size,
                              hipStream_t stream) {
  (void)in_sizes; (void)n_in; (void)out_size; (void)ws_size;
  const float* x     = (const float*)d_in[1];
  const float* gridp = (const float*)d_in[2];
  const float* feat  = (const float*)d_in[3];
  const float* Iinv  = (const float*)d_in[4];
  const float* Einv  = (const float*)d_in[5];
  const float* gfl   = (const float*)d_in[6];
  const float* bfl   = (const float*)d_in[7];
  const float* Wfl   = (const float*)d_in[8];
  const float* gfp   = (const float*)d_in[9];
  const float* bfp   = (const float*)d_in[10];
  const float* Wfp   = (const float*)d_in[11];
  const float* Wbev  = (const float*)d_in[12];
  const float* bbev  = (const float*)d_in[13];
  const float* Wimg  = (const float*)d_in[14];
  const float* Wcam  = (const float*)d_in[15];
  const float* alng  = (const float*)d_in[16];
  const float* alnb  = (const float*)d_in[17];
  const float* aWqkv = (const float*)d_in[18];
  const float* abqkv = (const float*)d_in[19];
  const float* aWp   = (const float*)d_in[20];
  const float* abp   = (const float*)d_in[21];
  const float* png   = (const float*)d_in[22];
  const float* pnb   = (const float*)d_in[23];
  const float* Wma   = (const float*)d_in[24];
  const float* bma   = (const float*)d_in[25];
  const float* Wmb   = (const float*)d_in[26];
  const float* bmb   = (const float*)d_in[27];
  const float* postg = (const float*)d_in[28];
  const float* postb = (const float*)d_in[29];
  float* out = (float*)d_out;
  float* ws  = (float*)d_ws;
  const float QSC = 0.17677669529663687f;

  unsigned short* Wt  = (unsigned short*)(ws + 2048);
  unsigned short* K1h = (unsigned short*)(ws + 149504);
  unsigned short* V1h = K1h + 4325376;
  unsigned short* KPh = V1h + 4325376;
  unsigned short* VPh = KPh + 4325376;
  unsigned short* QPh = VPh + 4325376;
  unsigned short* Qbh = QPh + 6291456;
  unsigned short* AOh = Qbh + 6291456;
  unsigned short* Hh  = AOh + 1048576;                 // 8192x256 bf16
  float* CURf = (float*)(Hh + 2097152);                // 8192x128 fp32
  float* Q1f  = CURf + 1048576;
  float* Q2f  = Q1f + 1048576;

  unsigned short* WtQ1 = Wt;            unsigned short* WtK1 = Wt + 16384;
  unsigned short* WtV1 = Wt + 32768;    unsigned short* WtQ2 = Wt + 49152;
  unsigned short* WtK2 = Wt + 65536;    unsigned short* WtV2 = Wt + 81920;
  unsigned short* WtP1 = Wt + 98304;    unsigned short* WtP2 = Wt + 114688;
  unsigned short* WtMA1 = Wt + 131072;  unsigned short* WtMA2 = Wt + 163840;
  unsigned short* WtMB1a = Wt + 196608; unsigned short* WtMB1b = Wt + 212992;
  unsigned short* WtMB2a = Wt + 229376; unsigned short* WtMB2b = Wt + 245760;
  unsigned short* WtFL = Wt + 262144;   unsigned short* WtFP = Wt + 278528;

  GArg Z{}; Z.oscale = 1.f;

  // 1) fused prep
  k_prep<<<10432, 128, 0, stream>>>(aWqkv, aWp, Wma, Wmb, Wfl, Wfp, Wt,
      Iinv, Einv, Wimg, Wcam, K1h, gridp, Wbev, bbev, x, alng, alnb, Qbh);

  // 2) conv K+V (persistent, 2 chunks/block)
  {
    GArg ck = Z, cv = Z;
    ck.Xf = feat; ck.conv = 1; ck.lg = gfp; ck.lb = bfp; ck.Wt = WtFP;
    ck.OUTH = K1h; ck.ldout = 128; ck.skip_mode = 2; ck.skiph = K1h;
    ck.ldskip = 128; ck.nchunks = 528; ck.nblocks = 264;
    cv = ck; cv.lg = gfl; cv.lb = bfl; cv.Wt = WtFL; cv.OUTH = V1h;
    cv.skip_mode = 0; cv.skiph = nullptr;
    k_gemmP<64><<<528, 256, 0, stream>>>(ck, cv, cv, 264, 528);
  }
  // 3) stage-1 Q+K+V projections (persistent, ~3.5 chunks/block)
  {
    GArg q = Z, kk = Z, vv = Z;
    q.Xh = Qbh; q.ldx = 128; q.Wt = WtQ1; q.bias = abqkv; q.OUTH = QPh;
    q.ldout = 128; q.oscale = QSC; q.nchunks = 768; q.nblocks = 224;
    kk.Xh = K1h; kk.ldx = 128; kk.do_ln = 1; kk.lg = alng+128; kk.lb = alnb+128;
    kk.Wt = WtK1; kk.bias = abqkv+128; kk.OUTH = KPh; kk.ldout = 128;
    kk.outmode = 1; kk.nchunks = 528; kk.nblocks = 144;
    vv = kk; vv.Xh = V1h; vv.lg = alng+256; vv.lb = alnb+256; vv.Wt = WtV1;
    vv.bias = abqkv+256; vv.OUTH = VPh;
    k_gemmP<64><<<512, 256, 0, stream>>>(q, kk, vv, 224, 368);
  }
  // 4) stage-1 attention
  k_attn2<<<512, 256, 0, stream>>>(QPh, KPh, VPh, AOh, 6, 384);
  // 5) stage-1 out-projection + x skip -> CURf (fp32)
  {
    GArg o = Z;
    o.Xh = AOh; o.ldx = 128; o.Wt = WtP1; o.bias = abp; o.OUTF = CURf;
    o.ldout = 128; o.skip_mode = 1; o.skipf = x; o.nchunks = 256; o.nblocks = 256;
    k_gemmP<32><<<256, 256, 0, stream>>>(o, o, o, 256, 256);
  }
  // 6) stage-1 MLP up (fp32 in, both halves)
  {
    GArg ma = Z, mb2 = Z;
    ma.Xf = CURf; ma.ldx = 128; ma.do_ln = 1; ma.lg = png; ma.lb = pnb;
    ma.Wt = WtMA1; ma.bias = bma; ma.OUTH = Hh; ma.ldout = 256; ma.act = 1;
    ma.nchunks = 256; ma.nblocks = 256;
    mb2 = ma; mb2.Wt = WtMA1+16384; mb2.bias = bma+128; mb2.OUTH = Hh+128;
    k_gemmP<32><<<512, 256, 0, stream>>>(ma, mb2, mb2, 256, 512);
  }
  // 7) stage-1 MLP down (KT=256) + CURf skip -> Q1f
  k_gemm256<<<256, 256, 0, stream>>>(Hh, WtMB1a, WtMB1b, bmb, Q1f, CURf);

  // 8) stage-2 Q+K+V projections
  {
    GArg q = Z, kk = Z, vv = Z;
    q.Xf = Q1f; q.ldx = 128; q.do_ln = 1; q.lg = alng+384; q.lb = alnb+384;
    q.Wt = WtQ2; q.bias = abqkv+384; q.OUTH = QPh; q.ldout = 128;
    q.oscale = QSC; q.nchunks = 128; q.nblocks = 64;
    kk.Xh = K1h; kk.ldx = 128; kk.do_ln = 1; kk.lg = alng+512; kk.lb = alnb+512;
    kk.Wt = WtK2; kk.bias = abqkv+512; kk.OUTH = KPh; kk.ldout = 128;
    kk.outmode = 2; kk.nchunks = 528; kk.nblocks = 224;
    vv = kk; vv.Xh = V1h; vv.lg = alng+640; vv.lb = alnb+640; vv.Wt = WtV2;
    vv.bias = abqkv+640; vv.OUTH = VPh;
    k_gemmP<64><<<512, 256, 0, stream>>>(q, kk, vv, 64, 288);
  }
  // 9) stage-2 attention
  k_attn2<<<512, 256, 0, stream>>>(QPh, KPh, VPh, AOh, 1, 64);
  // 10) stage-2 out-projection + Q1f skip -> CURf
  {
    GArg o = Z;
    o.Xh = AOh; o.ldx = 128; o.Wt = WtP2; o.bias = abp+128; o.OUTF = CURf;
    o.ldout = 128; o.skip_mode = 3; o.skipf = Q1f; o.ldskip = 128;
    o.nchunks = 256; o.nblocks = 256;
    k_gemmP<32><<<256, 256, 0, stream>>>(o, o, o, 256, 256);
  }
  // 11) stage-2 MLP up
  {
    GArg ma = Z, mb2 = Z;
    ma.Xf = CURf; ma.ldx = 128; ma.do_ln = 1; ma.lg = png+128; ma.lb = pnb+128;
    ma.Wt = WtMA2; ma.bias = bma+256; ma.OUTH = Hh; ma.ldout = 256; ma.act = 1;
    ma.nchunks = 256; ma.nblocks = 256;
    mb2 = ma; mb2.Wt = WtMA2+16384; mb2.bias = bma+384; mb2.OUTH = Hh+128;
    k_gemmP<32><<<512, 256, 0, stream>>>(ma, mb2, mb2, 256, 512);
  }
  // 12) stage-2 MLP down + CURf skip -> Q2f
  k_gemm256<<<256, 256, 0, stream>>>(Hh, WtMB2a, WtMB2b, bmb+128, Q2f, CURf);

  // 13) final LN + transpose
  k_final<<<1024, 128, 0, stream>>>(Q2f, postg, postb, out);
}

// Round 9
// 274.505 us; speedup vs baseline: 1.1624x; 1.1624x over previous
//
#include <hip/hip_runtime.h>
#include <math.h>

// CrossViewSwapAttention forward. Round 9 (corrected emit): row-local tail
// fusion, single-chunk gemms, camera-loop prep. 8 dispatches.
// conv-K adds the geom embedding via outmode==3 (accumulate into OUTH).

typedef __attribute__((ext_vector_type(8))) short short8;
typedef __attribute__((ext_vector_type(4))) float f32x4;

__device__ __forceinline__ unsigned short f2bf(float f){
  union { float f; unsigned u; } v; v.f = f;
  unsigned r = v.u + 0x7FFF + ((v.u >> 16) & 1);   // RNE
  return (unsigned short)(r >> 16);
}
__device__ __forceinline__ float bf2f(unsigned short h){
  union { unsigned u; float f; } v; v.u = ((unsigned)h) << 16; return v.f;
}
__device__ __forceinline__ void store_bf16x8(unsigned short* p, const float* v){
  union { short8 s8; unsigned short u[8]; } u;
  #pragma unroll
  for (int i=0;i<8;i++) u.u[i] = f2bf(v[i]);
  *(short8*)p = u.s8;
}

__device__ __forceinline__ float gelu_erf(float x){
  float z = x * 0.70710678118654752f;
  float a = fabsf(z);
  float t = 1.0f / fmaf(0.3275911f, a, 1.0f);
  float p = t*(0.254829592f + t*(-0.284496736f + t*(1.421413741f +
            t*(-1.453152027f + t*1.061405429f))));
  float er = 1.0f - p*__expf(-a*a);
  er = copysignf(er, z);
  return 0.5f * x * (1.0f + er);
}

__device__ __forceinline__ size_t remap_kv(int tok, int mode){
  int bn = tok / 2816; int p = tok - bn*2816;
  int b = bn / 6, n = bn - b*6;
  int i = p / 88, j = p - i*88;
  int l, t;
  if (mode == 1){
    int jw = j / 11;
    l = (i >> 2)*8 + jw;
    t = n*44 + (i & 3)*11 + (j - jw*11);
  } else {
    l = (i & 7)*8 + (j & 7);
    t = n*44 + (i >> 3)*11 + (j >> 3);
  }
  return (size_t)((b*64 + l)*264 + t);
}

__global__ __launch_bounds__(128) void k_prep(
    const float* __restrict__ qkv, const float* __restrict__ wp,
    const float* __restrict__ wma, const float* __restrict__ wmb,
    const float* __restrict__ wfl, const float* __restrict__ wfp,
    unsigned short* __restrict__ Wt,
    const float* __restrict__ Iinv, const float* __restrict__ Einv,
    const float* __restrict__ Wimg, const float* __restrict__ Wcam,
    unsigned short* __restrict__ K1h,
    const float* __restrict__ gridp, const float* __restrict__ Wbev,
    const float* __restrict__ bbev, const float* __restrict__ x,
    const float* __restrict__ lg, const float* __restrict__ lb,
    unsigned short* __restrict__ Qh){
  __shared__ float sx[128][9];
  int bid = blockIdx.x;
  if (bid < 64){
    const int sel[16]  = {0,0,0,0,0,0, 1,1, 2,2, 3,3,3,3, 4,5};
    const int soff[16] = {0,16384,32768,49152,65536,81920, 0,16384, 0,32768,
                          0,16384,32768,49152, 0,0};
    const int doff[16] = {0,16384,32768,49152,65536,81920, 98304,114688,
                          131072,163840, 196608,212992,229376,245760, 262144,278528};
    const int Ns[16]   = {128,128,128,128,128,128, 128,128, 256,256,
                          128,128,128,128, 128,128};
    const int trs[16]  = {1,1,1,1,1,1, 1,1, 1,1, 1,1,1,1, 0,0};
    int sg = bid >> 2, q = bid & 3;
    const float* srcs[6] = {qkv, wp, wma, wmb, wfl, wfp};
    const float* src = srcs[sel[sg]] + soff[sg];
    unsigned short* dst = Wt + doff[sg];
    int K = 128, N = Ns[sg];
    int quarter = (K*N) >> 2;
    for (int idx = q*quarter + threadIdx.x; idx < (q+1)*quarter; idx += 128){
      int n = idx / K, k = idx - n*K;
      float v = trs[sg] ? src[k*N + n] : src[idx];
      dst[idx] = f2bf(v);
    }
  } else if (bid < 4288){
    int tile = bid - 64;
    int bn = tile / 352; int p0 = (tile - bn*352)*8;
    int xid = threadIdx.x >> 4, part = threadIdx.x & 15;
    int p = p0 + xid;
    int i = p / 88, j = p - i*88;
    float xs = (float)j * (480.0f/87.0f);
    float ys = (float)i * (224.0f/31.0f);
    const float* I = Iinv + bn*9;
    const float* E = Einv + bn*16;
    float c0 = I[0]*xs + I[1]*ys + I[2];
    float c1 = I[3]*xs + I[4]*ys + I[5];
    float c2 = I[6]*xs + I[7]*ys + I[8];
    float d0 = E[0]*c0 + E[1]*c1 + E[2]*c2 + E[3];
    float d1 = E[4]*c0 + E[5]*c1 + E[6]*c2 + E[7];
    float d2 = E[8]*c0 + E[9]*c1 + E[10]*c2 + E[11];
    float d3 = E[12]*c0 + E[13]*c1 + E[14]*c2 + E[15];
    float v[8]; float sq = 0.f;
    #pragma unroll
    for (int k=0;k<8;k++){
      int o = part*8 + k;
      const float* W = Wimg + o*4;
      const float* Wc = Wcam + o*4;
      float de = W[0]*d0 + W[1]*d1 + W[2]*d2 + W[3]*d3;
      float ce = Wc[0]*E[3] + Wc[1]*E[7] + Wc[2]*E[11] + Wc[3]*E[15];
      float vv = de - ce;
      v[k] = vv; sq = fmaf(vv, vv, sq);
    }
    #pragma unroll
    for (int off=8; off>0; off>>=1) sq += __shfl_xor(sq, off, 16);
    float rn = 1.0f / fmaxf(sqrtf(sq), 1e-12f);
    float o8[8];
    #pragma unroll
    for (int k=0;k<8;k++) o8[k] = v[k]*rn;
    store_bf16x8(K1h + (size_t)(bn*2816 + p)*128 + part*8, o8);
  } else {
    int bid2 = bid - 4288;
    int b = bid2 >> 9; int pp0 = (bid2 & 511) << 3;
    {
      int cg = threadIdx.x >> 3, px = threadIdx.x & 7;
      #pragma unroll
      for (int i=0;i<8;i++){
        int c = cg + 16*i;
        sx[c][px] = x[(size_t)b*524288 + (size_t)c*4096 + pp0 + px];
      }
    }
    __syncthreads();
    int xid = threadIdx.x >> 4, part = threadIdx.x & 15;
    int pix = pp0 + xid;
    int h = pix >> 6, w = pix & 63;
    int l = (h>>3)*8 + (w>>3);
    int tq = (h&7)*8 + (w&7);
    float g0 = gridp[pix], g1 = gridp[4096 + pix];
    float we[8], xv[8];
    #pragma unroll
    for (int k=0;k<8;k++){
      int o = part*8 + k;
      we[k] = Wbev[o*2]*g0 + Wbev[o*2+1]*g1 + bbev[o];
      xv[k] = sx[part*8+k][xid];
    }
    for (int n=0; n<6; n++){
      const float* E = Einv + (b*6+n)*16;
      float v[8]; float sq = 0.f;
      #pragma unroll
      for (int k=0;k<8;k++){
        int o = part*8 + k;
        const float* Wc = Wcam + o*4;
        float ce = Wc[0]*E[3] + Wc[1]*E[7] + Wc[2]*E[11] + Wc[3]*E[15];
        float vv = we[k] - ce;
        v[k] = vv; sq = fmaf(vv, vv, sq);
      }
      #pragma unroll
      for (int off=8; off>0; off>>=1) sq += __shfl_xor(sq, off, 16);
      float rn = 1.0f / fmaxf(sqrtf(sq), 1e-12f);
      float q[8]; float s=0.f, s2=0.f;
      #pragma unroll
      for (int k=0;k<8;k++){
        q[k] = fmaf(v[k], rn, xv[k]);
        s += q[k]; s2 = fmaf(q[k], q[k], s2);
      }
      #pragma unroll
      for (int off=8; off>0; off>>=1){ s += __shfl_xor(s, off, 16); s2 += __shfl_xor(s2, off, 16); }
      float mean = s*(1.f/128.f);
      float rstd = rsqrtf(fmaxf(s2*(1.f/128.f) - mean*mean, 0.f) + 1e-5f);
      size_t row = (size_t)((b*64 + l)*384 + n*64 + tq);
      float o8[8];
      #pragma unroll
      for (int k=0;k<8;k++){
        int c = part*8 + k;
        o8[k] = fmaf((q[k]-mean)*rstd, lg[c], lb[c]);
      }
      store_bf16x8(Qh + row*128 + part*8, o8);
    }
  }
}

struct GArg {
  const unsigned short* Xh; const float* Xf; int ldx;
  const float* lg; const float* lb;
  const unsigned short* Wt; const float* bias;
  unsigned short* OUTH; int ldout; float oscale;
  int do_ln; int outmode; int conv;     // outmode: 0 none,1/2 remap,3 add-in-place
};

template<int MT>
__global__ __launch_bounds__(256) void k_gemm3(GArg ga, GArg gb, GArg gc,
                                               int s1, int s2){
  constexpr int KP_ = 136;
  constexpr int MTILES = MT / 16;
  constexpr int TPR = 256 / MT;
  constexpr int KPT = 128 / TPR;
  __shared__ unsigned short sW[128*KP_];
  __shared__ unsigned short sA[MT*KP_];
  __shared__ float sg[128], sb[128], sbias[128];
  const int b0 = (int)blockIdx.x;
  const GArg g = (b0 < s1) ? ga : (b0 < s2) ? gb : gc;
  const int bid = (b0 < s1) ? b0 : (b0 < s2) ? b0 - s1 : b0 - s2;
  const int base = bid * MT;
  const int tid = threadIdx.x;
  for (int i = tid; i < 2048; i += 256){
    int n = i >> 4, k8 = (i & 15) << 3;
    *(short8*)&sW[n*KP_ + k8] = *(const short8*)(g.Wt + (size_t)n*128 + k8);
  }
  if (tid < 128){
    if (g.do_ln || g.conv){ sg[tid]=g.lg[tid]; sb[tid]=g.lb[tid]; }
    sbias[tid] = g.bias ? g.bias[tid] : 0.f;
  }
  const float RSQ = rsqrtf(1.0f + 1e-5f);
  if (g.conv){
    int prow = tid & 63, cseg = tid >> 6;
    int bn = base / 2816;
    int p = base - bn*2816 + prow;
    const float* fb = g.Xf + ((size_t)bn*128 + cseg*32)*2816 + p;
    #pragma unroll
    for (int i=0;i<32;i+=2){
      int c = cseg*32 + i;
      float t0 = fb[(size_t)i*2816] * RSQ;
      float t1 = fb[(size_t)(i+1)*2816] * RSQ;
      float y0 = fmaxf(fmaf(t0, sg[c],   sb[c]),   0.f);
      float y1 = fmaxf(fmaf(t1, sg[c+1], sb[c+1]), 0.f);
      unsigned u = (unsigned)f2bf(y0) | ((unsigned)f2bf(y1) << 16);
      *(unsigned*)&sA[prow*KP_ + c] = u;
    }
  } else {
    const int r = tid / TPR, part = tid % TPR;
    unsigned short* dst = sA + r*KP_ + part*KPT;
    float v[KPT];
    if (g.Xf){
      const float* src = g.Xf + (size_t)(base+r)*g.ldx + part*KPT;
      #pragma unroll
      for (int k=0;k<KPT;k+=4){
        float4 t = *(const float4*)(src + k);
        v[k]=t.x; v[k+1]=t.y; v[k+2]=t.z; v[k+3]=t.w;
      }
    } else {
      const unsigned short* src = g.Xh + (size_t)(base+r)*g.ldx + part*KPT;
      #pragma unroll
      for (int k=0;k<KPT;k+=8){
        union { short8 s; unsigned short u[8]; } t;
        t.s = *(const short8*)(src+k);
        #pragma unroll
        for (int i2=0;i2<8;i2++) v[k+i2] = bf2f(t.u[i2]);
      }
    }
    if (g.do_ln){
      float s=0.f, s2=0.f;
      #pragma unroll
      for (int k=0;k<KPT;k++){ s += v[k]; s2 = fmaf(v[k],v[k],s2); }
      #pragma unroll
      for (int off=TPR/2; off>0; off>>=1){
        s += __shfl_xor(s, off, TPR); s2 += __shfl_xor(s2, off, TPR);
      }
      float mean = s * (1.f/128.f);
      float rstd = rsqrtf(fmaxf(s2*(1.f/128.f) - mean*mean, 0.f) + 1e-5f);
      #pragma unroll
      for (int k=0;k<KPT;k++){
        int c = part*KPT + k;
        v[k] = fmaf((v[k]-mean)*rstd, sg[c], sb[c]);
      }
    }
    #pragma unroll
    for (int k=0;k<KPT;k+=8) store_bf16x8(dst+k, v+k);
  }
  __syncthreads();
  const int lane = tid & 63, wv = tid >> 6;
  const int lane15 = lane & 15, quad = lane >> 4;
  const int n0 = wv * 32;
  f32x4 acc[MTILES][2];
  #pragma unroll
  for (int mt=0; mt<MTILES; mt++){ acc[mt][0]=(f32x4)0.f; acc[mt][1]=(f32x4)0.f; }
  const unsigned short* aptr = sA + lane15*KP_ + quad*8;
  const unsigned short* bptr = sW + (size_t)(n0 + lane15)*KP_ + quad*8;
  #pragma unroll
  for (int kk=0; kk<4; kk++){
    short8 af[MTILES], bf2v[2];
    #pragma unroll
    for (int mt=0; mt<MTILES; mt++) af[mt] = *(const short8*)(aptr + mt*16*KP_ + kk*32);
    bf2v[0] = *(const short8*)(bptr + kk*32);
    bf2v[1] = *(const short8*)(bptr + 16*KP_ + kk*32);
    #pragma unroll
    for (int mt=0; mt<MTILES; mt++){
      acc[mt][0] = __builtin_amdgcn_mfma_f32_16x16x32_bf16(af[mt], bf2v[0], acc[mt][0], 0,0,0);
      acc[mt][1] = __builtin_amdgcn_mfma_f32_16x16x32_bf16(af[mt], bf2v[1], acc[mt][1], 0,0,0);
    }
  }
  __syncthreads();
  #pragma unroll
  for (int mt=0; mt<MTILES; mt++){
    #pragma unroll
    for (int nt=0; nt<2; nt++){
      int col = n0 + nt*16 + lane15;
      float bsv = sbias[col];
      #pragma unroll
      for (int r4=0; r4<4; r4++){
        int row = mt*16 + quad*4 + r4;
        float v = (acc[mt][nt][r4] + bsv) * g.oscale;
        if (g.outmode == 3)
          v += bf2f(g.OUTH[(size_t)(base+row)*g.ldout + col]);
        sA[row*KP_ + col] = f2bf(v);
      }
    }
  }
  __syncthreads();
  for (int i = tid; i < MT*16; i += 256){
    int row = i >> 4, seg = i & 15;
    int rrow = base + row;
    size_t orow = (g.outmode==1||g.outmode==2) ? remap_kv(rrow, g.outmode) : (size_t)rrow;
    *(short8*)(g.OUTH + orow*(size_t)g.ldout + seg*8) = *(const short8*)&sA[row*KP_ + seg*8];
  }
}

__global__ __launch_bounds__(256) void k_tail(
    const unsigned short* __restrict__ AOh,
    const float* __restrict__ skipf, int skipmode,
    const unsigned short* __restrict__ WtP, const float* __restrict__ abp,
    const float* __restrict__ png, const float* __restrict__ pnb,
    const unsigned short* __restrict__ WtMAa, const unsigned short* __restrict__ WtMAb,
    const float* __restrict__ bma,
    const unsigned short* __restrict__ WtMBa, const unsigned short* __restrict__ WtMBb,
    const float* __restrict__ bmb,
    float* __restrict__ Q1out,
    const float* __restrict__ postg, const float* __restrict__ postb,
    float* __restrict__ out){
  constexpr int KP_ = 136;
  __shared__ unsigned short sW[128*KP_];
  __shared__ unsigned short sX[32*KP_];
  __shared__ unsigned short sH1[32*KP_];
  __shared__ unsigned short sH2[32*KP_];
  __shared__ float sCUR[32*132];
  __shared__ float sbias[128];
  __shared__ float sg[128], sb2[128];
  __shared__ float sMean[32], sRstd[32];
  const int tid = threadIdx.x;
  const int base = blockIdx.x * 32;
  const int lane = tid & 63, wv = tid >> 6;
  const int lane15 = lane & 15, quad = lane >> 4;
  const int n0 = wv * 32;

  auto loadW = [&](const unsigned short* Wp){
    for (int i = tid; i < 2048; i += 256){
      int n = i >> 4, k8 = (i & 15) << 3;
      *(short8*)&sW[n*KP_ + k8] = *(const short8*)(Wp + (size_t)n*128 + k8);
    }
  };
  auto domfma = [&](const unsigned short* Asrc, f32x4 acc[2][2]){
    const unsigned short* aptr = Asrc + lane15*KP_ + quad*8;
    const unsigned short* bptr = sW + (size_t)(n0 + lane15)*KP_ + quad*8;
    #pragma unroll
    for (int kk=0; kk<4; kk++){
      short8 a0 = *(const short8*)(aptr + kk*32);
      short8 a1 = *(const short8*)(aptr + 16*KP_ + kk*32);
      short8 b0 = *(const short8*)(bptr + kk*32);
      short8 b1 = *(const short8*)(bptr + 16*KP_ + kk*32);
      acc[0][0] = __builtin_amdgcn_mfma_f32_16x16x32_bf16(a0,b0,acc[0][0],0,0,0);
      acc[1][0] = __builtin_amdgcn_mfma_f32_16x16x32_bf16(a1,b0,acc[1][0],0,0,0);
      acc[0][1] = __builtin_amdgcn_mfma_f32_16x16x32_bf16(a0,b1,acc[0][1],0,0,0);
      acc[1][1] = __builtin_amdgcn_mfma_f32_16x16x32_bf16(a1,b1,acc[1][1],0,0,0);
    }
  };

  loadW(WtP);
  {
    const int r = tid >> 3, part = tid & 7;
    const short8* src = (const short8*)(AOh + (size_t)(base+r)*128 + part*16);
    short8* dst = (short8*)(sX + r*KP_ + part*16);
    dst[0] = src[0]; dst[1] = src[1];
  }
  if (tid < 128){ sbias[tid] = abp[tid]; sg[tid] = png[tid]; sb2[tid] = pnb[tid]; }
  __syncthreads();
  {
    f32x4 acc[2][2];
    acc[0][0]=(f32x4)0.f; acc[0][1]=(f32x4)0.f;
    acc[1][0]=(f32x4)0.f; acc[1][1]=(f32x4)0.f;
    domfma(sX, acc);
    #pragma unroll
    for (int mt=0; mt<2; mt++)
      #pragma unroll
      for (int nt=0; nt<2; nt++){
        int col = n0 + nt*16 + lane15;
        float bsv = sbias[col];
        #pragma unroll
        for (int r4=0; r4<4; r4++){
          int row = mt*16 + quad*4 + r4;
          int rrow = base + row;
          float v = acc[mt][nt][r4] + bsv;
          if (skipmode == 1){
            int bb = rrow >> 12, l = (rrow >> 6) & 63, pp = rrow & 63;
            int pix = (((l>>3)*8 + (pp>>3)) << 6) + (l&7)*8 + (pp&7);
            v += skipf[(size_t)bb*524288 + (size_t)col*4096 + pix];
          } else {
            v += skipf[(size_t)rrow*128 + col];
          }
          sCUR[row*132 + col] = v;
        }
      }
  }
  __syncthreads();
  loadW(WtMAa);
  if (tid < 128) sbias[tid] = bma[tid];
  {
    const int r = tid >> 3, part = tid & 7;
    float v[16];
    #pragma unroll
    for (int k=0;k<16;k++) v[k] = sCUR[r*132 + part*16 + k];
    float s=0.f, s2=0.f;
    #pragma unroll
    for (int k=0;k<16;k++){ s += v[k]; s2 = fmaf(v[k],v[k],s2); }
    #pragma unroll
    for (int off=4; off>0; off>>=1){ s += __shfl_xor(s, off, 8); s2 += __shfl_xor(s2, off, 8); }
    float mean = s*(1.f/128.f);
    float rstd = rsqrtf(fmaxf(s2*(1.f/128.f) - mean*mean, 0.f) + 1e-5f);
    #pragma unroll
    for (int k=0;k<16;k++){
      int c = part*16 + k;
      v[k] = fmaf((v[k]-mean)*rstd, sg[c], sb2[c]);
    }
    store_bf16x8(sX + r*KP_ + part*16, v);
    store_bf16x8(sX + r*KP_ + part*16 + 8, v+8);
  }
  __syncthreads();
  {
    f32x4 acc[2][2];
    acc[0][0]=(f32x4)0.f; acc[0][1]=(f32x4)0.f;
    acc[1][0]=(f32x4)0.f; acc[1][1]=(f32x4)0.f;
    domfma(sX, acc);
    #pragma unroll
    for (int mt=0; mt<2; mt++)
      #pragma unroll
      for (int nt=0; nt<2; nt++){
        int col = n0 + nt*16 + lane15;
        float bsv = sbias[col];
        #pragma unroll
        for (int r4=0; r4<4; r4++){
          int row = mt*16 + quad*4 + r4;
          sH1[row*KP_ + col] = f2bf(gelu_erf(acc[mt][nt][r4] + bsv));
        }
      }
  }
  __syncthreads();
  loadW(WtMAb);
  if (tid < 128) sbias[tid] = bma[128 + tid];
  __syncthreads();
  {
    f32x4 acc[2][2];
    acc[0][0]=(f32x4)0.f; acc[0][1]=(f32x4)0.f;
    acc[1][0]=(f32x4)0.f; acc[1][1]=(f32x4)0.f;
    domfma(sX, acc);
    #pragma unroll
    for (int mt=0; mt<2; mt++)
      #pragma unroll
      for (int nt=0; nt<2; nt++){
        int col = n0 + nt*16 + lane15;
        float bsv = sbias[col];
        #pragma unroll
        for (int r4=0; r4<4; r4++){
          int row = mt*16 + quad*4 + r4;
          sH2[row*KP_ + col] = f2bf(gelu_erf(acc[mt][nt][r4] + bsv));
        }
      }
  }
  __syncthreads();
  loadW(WtMBa);
  if (tid < 128) sbias[tid] = bmb[tid];
  __syncthreads();
  f32x4 acc[2][2];
  acc[0][0]=(f32x4)0.f; acc[0][1]=(f32x4)0.f;
  acc[1][0]=(f32x4)0.f; acc[1][1]=(f32x4)0.f;
  domfma(sH1, acc);
  __syncthreads();
  loadW(WtMBb);
  __syncthreads();
  domfma(sH2, acc);
  if (out == nullptr){
    #pragma unroll
    for (int mt=0; mt<2; mt++)
      #pragma unroll
      for (int nt=0; nt<2; nt++){
        int col = n0 + nt*16 + lane15;
        float bsv = sbias[col];
        #pragma unroll
        for (int r4=0; r4<4; r4++){
          int row = mt*16 + quad*4 + r4;
          Q1out[(size_t)(base+row)*128 + col] = acc[mt][nt][r4] + bsv + sCUR[row*132 + col];
        }
      }
  } else {
    float res[2][2][4];
    #pragma unroll
    for (int mt=0; mt<2; mt++)
      #pragma unroll
      for (int nt=0; nt<2; nt++){
        int col = n0 + nt*16 + lane15;
        float bsv = sbias[col];
        #pragma unroll
        for (int r4=0; r4<4; r4++){
          int row = mt*16 + quad*4 + r4;
          res[mt][nt][r4] = acc[mt][nt][r4] + bsv + sCUR[row*132 + col];
        }
      }
    __syncthreads();
    #pragma unroll
    for (int mt=0; mt<2; mt++)
      #pragma unroll
      for (int nt=0; nt<2; nt++){
        int col = n0 + nt*16 + lane15;
        #pragma unroll
        for (int r4=0; r4<4; r4++){
          int row = mt*16 + quad*4 + r4;
          sCUR[row*132 + col] = res[mt][nt][r4];
        }
      }
    __syncthreads();
    {
      const int r = tid >> 3, part = tid & 7;
      float v[16];
      #pragma unroll
      for (int k=0;k<16;k++) v[k] = sCUR[r*132 + part*16 + k];
      float s=0.f, s2=0.f;
      #pragma unroll
      for (int k=0;k<16;k++){ s += v[k]; s2 = fmaf(v[k],v[k],s2); }
      #pragma unroll
      for (int off=4; off>0; off>>=1){ s += __shfl_xor(s, off, 8); s2 += __shfl_xor(s2, off, 8); }
      if (part == 0){
        float mean = s*(1.f/128.f);
        sMean[r] = mean;
        sRstd[r] = rsqrtf(fmaxf(s2*(1.f/128.f) - mean*mean, 0.f) + 1e-5f);
      }
    }
    __syncthreads();
    {
      int c = tid & 127, half = tid >> 7;
      int b = base >> 12, l = (base >> 6) & 63, p0 = base & 63;
      float go = postg[c], bo = postb[c];
      #pragma unroll
      for (int seg=0; seg<2; seg++){
        int p = p0 + half*16 + seg*8;
        int hrow = (l>>3)*8 + (p>>3);
        int w0 = (l&7)*8;
        float rr[8];
        #pragma unroll
        for (int j=0;j<8;j++){
          int row = half*16 + seg*8 + j;
          rr[j] = fmaf((sCUR[row*132 + c] - sMean[row])*sRstd[row], go, bo);
        }
        size_t obase = ((size_t)(b*128 + c))*4096 + (size_t)hrow*64 + w0;
        *(float4*)&out[obase]   = make_float4(rr[0],rr[1],rr[2],rr[3]);
        *(float4*)&out[obase+4] = make_float4(rr[4],rr[5],rr[6],rr[7]);
      }
    }
  }
}

__global__ __launch_bounds__(256) void k_attn2(const unsigned short* __restrict__ QPh,
    const unsigned short* __restrict__ KPh, const unsigned short* __restrict__ VPh,
    unsigned short* __restrict__ AOh, int nrep, int nQ){
  __shared__ unsigned short Ksh[288*40];
  __shared__ unsigned short Vt[32*296];
  __shared__ unsigned short Psh[4*16*40];
  __shared__ float rs[4*16];
  int hd = blockIdx.x & 3; int bl = blockIdx.x >> 2;
  size_t kvbase = (size_t)bl*264;
  int tid = threadIdx.x;
  for (int idx = tid; idx < 1056; idx += 256){
    int row = idx >> 2, seg = idx & 3;
    *(short8*)&Ksh[row*40 + seg*8] =
      *(const short8*)(KPh + (kvbase+row)*128 + hd*32 + seg*8);
  }
  for (int idx = tid; idx < 96; idx += 256){
    int row = 264 + (idx>>2), seg = idx & 3;
    short8 z = {0,0,0,0,0,0,0,0};
    *(short8*)&Ksh[row*40 + seg*8] = z;
  }
  for (int idx = tid; idx < 1056; idx += 256){
    int row = idx >> 2, seg = idx & 3;
    union { short8 s; unsigned short u[8]; } t;
    t.s = *(const short8*)(VPh + (kvbase+row)*128 + hd*32 + seg*8);
    #pragma unroll
    for (int i=0;i<8;i++) Vt[(seg*8+i)*296 + row] = t.u[i];
  }
  for (int idx = tid; idx < 384; idx += 256){
    int d = idx / 12, kp = 264 + (idx % 12)*2;
    *(unsigned*)&Vt[d*296 + kp] = 0u;
  }
  __syncthreads();
  const int wv = tid >> 6, lane = tid & 63;
  const int lane15 = lane & 15, quad = lane >> 4;
  unsigned short* Pw = Psh + wv*640;
  float* rsw = rs + wv*16;
  short8 vfrag[9][2];
  #pragma unroll
  for (int kc=0; kc<9; kc++){
    vfrag[kc][0] = *(const short8*)&Vt[(lane15)*296      + kc*32 + quad*8];
    vfrag[kc][1] = *(const short8*)&Vt[(16+lane15)*296   + kc*32 + quad*8];
  }
  f32x4 macc0 = (f32x4)0.f, macc1 = (f32x4)0.f;
  for (int cam = 0; cam < nrep; cam++){
    int qrow = bl*nQ + (cam*4 + wv)*16 + lane15;
    short8 qf = *(const short8*)(QPh + (size_t)qrow*128 + hd*32 + quad*8);
    f32x4 oa0 = (f32x4)0.f, oa1 = (f32x4)0.f;
    float rsum = 0.f;
    #pragma unroll
    for (int kc=0; kc<9; kc++){
      #pragma unroll
      for (int sub=0; sub<2; sub++){
        int kt = kc*2 + sub;
        short8 kf = *(const short8*)&Ksh[(kt*16 + lane15)*40 + quad*8];
        f32x4 st = __builtin_amdgcn_mfma_f32_16x16x32_bf16(kf, qf, (f32x4)0.f, 0,0,0);
        int kbase = kt*16 + quad*4;
        float e0 = (kbase+0 < 264) ? __expf(st[0]) : 0.f;
        float e1 = (kbase+1 < 264) ? __expf(st[1]) : 0.f;
        float e2 = (kbase+2 < 264) ? __expf(st[2]) : 0.f;
        float e3 = (kbase+3 < 264) ? __expf(st[3]) : 0.f;
        rsum += (e0+e1)+(e2+e3);
        uint2 pk;
        pk.x = (unsigned)f2bf(e0) | ((unsigned)f2bf(e1) << 16);
        pk.y = (unsigned)f2bf(e2) | ((unsigned)f2bf(e3) << 16);
        *(uint2*)&Pw[lane15*40 + sub*16 + quad*4] = pk;
      }
      short8 pf = *(const short8*)&Pw[lane15*40 + quad*8];
      oa0 = __builtin_amdgcn_mfma_f32_16x16x32_bf16(pf, vfrag[kc][0], oa0, 0,0,0);
      oa1 = __builtin_amdgcn_mfma_f32_16x16x32_bf16(pf, vfrag[kc][1], oa1, 0,0,0);
    }
    rsum += __shfl_xor(rsum, 16);
    rsum += __shfl_xor(rsum, 32);
    if (lane < 16) rsw[lane] = rsum;
    f32x4 rv = *(f32x4*)&rsw[quad*4];
    #pragma unroll
    for (int r=0;r<4;r++){
      float inv = 1.f / rv[r];
      macc0[r] = fmaf(oa0[r], inv, macc0[r]);
      macc1[r] = fmaf(oa1[r], inv, macc1[r]);
    }
  }
  float sc = (nrep == 6) ? (1.f/6.f) : 1.f;
  int pixb = wv*16 + quad*4;
  #pragma unroll
  for (int r=0;r<4;r++){
    size_t rowo = ((size_t)(bl*64 + pixb + r))*128 + hd*32;
    AOh[rowo + lane15]      = f2bf(macc0[r]*sc);
    AOh[rowo + 16 + lane15] = f2bf(macc1[r]*sc);
  }
}

extern "C" void kernel_launch(void* const* d_in, const int* in_sizes, int n_in,
                              void* d_out, int out_size, void* d_ws, size_t ws_size,
                              hipStream_t stream) {
  (void)in_sizes; (void)n_in; (void)out_size; (void)ws_size;
  const float* x     = (const float*)d_in[1];
  const float* gridp = (const float*)d_in[2];
  const float* feat  = (const float*)d_in[3];
  const float* Iinv  = (const float*)d_in[4];
  const float* Einv  = (const float*)d_in[5];
  const float* gfl   = (const float*)d_in[6];
  const float* bfl   = (const float*)d_in[7];
  const float* Wfl   = (const float*)d_in[8];
  const float* gfp   = (const float*)d_in[9];
  const float* bfp   = (const float*)d_in[10];
  const float* Wfp   = (const float*)d_in[11];
  const float* Wbev  = (const float*)d_in[12];
  const float* bbev  = (const float*)d_in[13];
  const float* Wimg  = (const float*)d_in[14];
  const float* Wcam  = (const float*)d_in[15];
  const float* alng  = (const float*)d_in[16];
  const float* alnb  = (const float*)d_in[17];
  const float* aWqkv = (const float*)d_in[18];
  const float* abqkv = (const float*)d_in[19];
  const float* aWp   = (const float*)d_in[20];
  const float* abp   = (const float*)d_in[21];
  const float* png   = (const float*)d_in[22];
  const float* pnb   = (const float*)d_in[23];
  const float* Wma   = (const float*)d_in[24];
  const float* bma   = (const float*)d_in[25];
  const float* Wmb   = (const float*)d_in[26];
  const float* bmb   = (const float*)d_in[27];
  const float* postg = (const float*)d_in[28];
  const float* postb = (const float*)d_in[29];
  float* out = (float*)d_out;
  float* ws  = (float*)d_ws;
  const float QSC = 0.17677669529663687f;

  unsigned short* Wt  = (unsigned short*)(ws + 2048);
  unsigned short* K1h = (unsigned short*)(ws + 149504);
  unsigned short* V1h = K1h + 4325376;
  unsigned short* KPh = V1h + 4325376;
  unsigned short* VPh = KPh + 4325376;
  unsigned short* QPh = VPh + 4325376;
  unsigned short* Qbh = QPh + 6291456;
  unsigned short* AOh = Qbh + 6291456;
  float* Q1f = (float*)(AOh + 1048576);

  unsigned short* WtQ1 = Wt;            unsigned short* WtK1 = Wt + 16384;
  unsigned short* WtV1 = Wt + 32768;    unsigned short* WtQ2 = Wt + 49152;
  unsigned short* WtK2 = Wt + 65536;    unsigned short* WtV2 = Wt + 81920;
  unsigned short* WtP1 = Wt + 98304;    unsigned short* WtP2 = Wt + 114688;
  unsigned short* WtMA1 = Wt + 131072;  unsigned short* WtMA2 = Wt + 163840;
  unsigned short* WtMB1a = Wt + 196608; unsigned short* WtMB1b = Wt + 212992;
  unsigned short* WtMB2a = Wt + 229376; unsigned short* WtMB2b = Wt + 245760;
  unsigned short* WtFL = Wt + 262144;   unsigned short* WtFP = Wt + 278528;

  GArg Z{}; Z.oscale = 1.f;

  k_prep<<<5312, 128, 0, stream>>>(aWqkv, aWp, Wma, Wmb, Wfl, Wfp, Wt,
      Iinv, Einv, Wimg, Wcam, K1h, gridp, Wbev, bbev, x, alng, alnb, Qbh);

  // conv: K-role accumulates into K1h (outmode 3), V-role plain write
  {
    GArg ck = Z, cv = Z;
    ck.Xf = feat; ck.conv = 1; ck.lg = gfp; ck.lb = bfp; ck.Wt = WtFP;
    ck.OUTH = K1h; ck.ldout = 128; ck.outmode = 3;
    cv = ck; cv.lg = gfl; cv.lb = bfl; cv.Wt = WtFL; cv.OUTH = V1h;
    cv.outmode = 0;
    k_gemm3<64><<<1056, 256, 0, stream>>>(ck, cv, cv, 528, 1056);
  }
  {
    GArg q = Z, kk = Z, vv = Z;
    q.Xh = Qbh; q.ldx = 128; q.Wt = WtQ1; q.bias = abqkv; q.OUTH = QPh;
    q.ldout = 128; q.oscale = QSC;
    kk.Xh = K1h; kk.ldx = 128; kk.do_ln = 1; kk.lg = alng+128; kk.lb = alnb+128;
    kk.Wt = WtK1; kk.bias = abqkv+128; kk.OUTH = KPh; kk.ldout = 128;
    kk.outmode = 1;
    vv = kk; vv.Xh = V1h; vv.lg = alng+256; vv.lb = alnb+256; vv.Wt = WtV1;
    vv.bias = abqkv+256; vv.OUTH = VPh;
    k_gemm3<64><<<1824, 256, 0, stream>>>(q, kk, vv, 768, 1296);
  }
  k_attn2<<<512, 256, 0, stream>>>(QPh, KPh, VPh, AOh, 6, 384);
  k_tail<<<256, 256, 0, stream>>>(AOh, x, 1, WtP1, abp, png, pnb,
      WtMA1, WtMA1+16384, bma, WtMB1a, WtMB1b, bmb, Q1f,
      nullptr, nullptr, nullptr);
  {
    GArg q = Z, kk = Z, vv = Z;
    q.Xf = Q1f; q.ldx = 128; q.do_ln = 1; q.lg = alng+384; q.lb = alnb+384;
    q.Wt = WtQ2; q.bias = abqkv+384; q.OUTH = QPh; q.ldout = 128;
    q.oscale = QSC;
    kk.Xh = K1h; kk.ldx = 128; kk.do_ln = 1; kk.lg = alng+512; kk.lb = alnb+512;
    kk.Wt = WtK2; kk.bias = abqkv+512; kk.OUTH = KPh; kk.ldout = 128;
    kk.outmode = 2;
    vv = kk; vv.Xh = V1h; vv.lg = alng+640; vv.lb = alnb+640; vv.Wt = WtV2;
    vv.bias = abqkv+640; vv.OUTH = VPh;
    k_gemm3<64><<<1184, 256, 0, stream>>>(q, kk, vv, 128, 656);
  }
  k_attn2<<<512, 256, 0, stream>>>(QPh, KPh, VPh, AOh, 1, 64);
  k_tail<<<256, 256, 0, stream>>>(AOh, Q1f, 3, WtP2, abp+128, png+128, pnb+128,
      WtMA2, WtMA2+16384, bma+256, WtMB2a, WtMB2b, bmb+128, nullptr,
      postg, postb, out);
}